// Round 2
// baseline (372.062 us; speedup 1.0000x reference)
//
#include <hip/hip_runtime.h>
#include <hip/hip_bf16.h>

using bf16 = __bf16;
using bf16x4 = __attribute__((ext_vector_type(4))) __bf16;
using bf16x8 = __attribute__((ext_vector_type(8))) __bf16;
using f32x4 = __attribute__((ext_vector_type(4))) float;

#define EXP2F(x) __builtin_amdgcn_exp2f(x)

// ---------------- prep: fp32 -> bf16 elementwise ----------------
__global__ __launch_bounds__(256) void cvt_kernel(const float4* __restrict__ in,
                                                  bf16x4* __restrict__ out, int n4) {
  int g = blockIdx.x * blockDim.x + threadIdx.x;
  if (g < n4) {
    float4 v = in[g];
    bf16x4 o = {(bf16)v.x, (bf16)v.y, (bf16)v.z, (bf16)v.w};
    out[g] = o;
  }
}

// ---------------- prep: W[k][n] fp32 -> Wt[n][k] bf16 ----------------
__global__ __launch_bounds__(256) void transpose_kernel(const float* __restrict__ w,
                                                        bf16* __restrict__ wt) {
  __shared__ float tile[32][33];
  int k0 = blockIdx.y * 32, n0 = blockIdx.x * 32;
  int tx = threadIdx.x, ty = threadIdx.y;
#pragma unroll
  for (int i = 0; i < 4; i++)
    tile[ty + i * 8][tx] = w[(size_t)(k0 + ty + i * 8) * 1024 + n0 + tx];
  __syncthreads();
#pragma unroll
  for (int i = 0; i < 4; i++)
    wt[(size_t)(n0 + ty + i * 8) * 1024 + k0 + tx] = (bf16)tile[tx][ty + i * 8];
}

// ---------------- GEMM: C[m][n] = A[m][k] * Wt[n][k]^T + bias ----------------
// A: [M][1024] bf16 ; Bt: [1024][1024] bf16 (n-major, k contiguous)
// MODE 0: out bf16, head-split [(b*16+h)*2048 + t][64]
// MODE 1: out bf16, V-transposed [((b*16+h)*64 + d)][2048] (col s)
// MODE 2: out fp32, plain [m][1024]
template <int MODE>
__global__ __launch_bounds__(256) void gemm_kernel(const bf16* __restrict__ A,
                                                   const bf16* __restrict__ Bt,
                                                   const float* __restrict__ bias,
                                                   void* __restrict__ outp) {
  constexpr int K = 1024;
  __shared__ __align__(16) char smem[34816];
  bf16(*As)[40] = (bf16(*)[40])smem;
  bf16(*Bs)[40] = (bf16(*)[40])(smem + 10240);
  bf16(*Cs)[136] = (bf16(*)[136])smem;

  const int tid = threadIdx.x;
  const int lane = tid & 63;
  const int w = tid >> 6;
  const int wr = w >> 1, wc = w & 1;
  const int m0 = blockIdx.y * 128, n0 = blockIdx.x * 128;
  const int fr = lane & 15, fg = (lane >> 4) * 8;

  f32x4 acc[4][4] = {};

  const int srow = tid >> 2;             // 0..63
  const int kc = (tid & 3) * 8;          // 0,8,16,24
  const int arow = m0 + srow, brow = n0 + srow;

  bf16x8 ra0, ra1, rb0, rb1;
  ra0 = *(const bf16x8*)&A[(size_t)arow * K + kc];
  ra1 = *(const bf16x8*)&A[(size_t)(arow + 64) * K + kc];
  rb0 = *(const bf16x8*)&Bt[(size_t)brow * K + kc];
  rb1 = *(const bf16x8*)&Bt[(size_t)(brow + 64) * K + kc];

  for (int k0 = 0; k0 < K; k0 += 32) {
    __syncthreads();
    *(bf16x8*)&As[srow][kc] = ra0;
    *(bf16x8*)&As[srow + 64][kc] = ra1;
    *(bf16x8*)&Bs[srow][kc] = rb0;
    *(bf16x8*)&Bs[srow + 64][kc] = rb1;
    if (k0 + 32 < K) {
      int kn = k0 + 32 + kc;
      ra0 = *(const bf16x8*)&A[(size_t)arow * K + kn];
      ra1 = *(const bf16x8*)&A[(size_t)(arow + 64) * K + kn];
      rb0 = *(const bf16x8*)&Bt[(size_t)brow * K + kn];
      rb1 = *(const bf16x8*)&Bt[(size_t)(brow + 64) * K + kn];
    }
    __syncthreads();
    bf16x8 af[4], bfr[4];
#pragma unroll
    for (int mi = 0; mi < 4; mi++)
      af[mi] = *(const bf16x8*)&As[wr * 64 + mi * 16 + fr][fg];
#pragma unroll
    for (int ni = 0; ni < 4; ni++)
      bfr[ni] = *(const bf16x8*)&Bs[wc * 64 + ni * 16 + fr][fg];
#pragma unroll
    for (int mi = 0; mi < 4; mi++)
#pragma unroll
      for (int ni = 0; ni < 4; ni++)
        acc[mi][ni] =
            __builtin_amdgcn_mfma_f32_16x16x32_bf16(af[mi], bfr[ni], acc[mi][ni], 0, 0, 0);
  }

  // bias
  float bv[4];
#pragma unroll
  for (int ni = 0; ni < 4; ni++) bv[ni] = bias[n0 + wc * 64 + ni * 16 + fr];
#pragma unroll
  for (int mi = 0; mi < 4; mi++)
#pragma unroll
    for (int ni = 0; ni < 4; ni++)
#pragma unroll
      for (int j = 0; j < 4; j++) acc[mi][ni][j] += bv[ni];

  if (MODE == 2) {
    float* O = (float*)outp;
#pragma unroll
    for (int mi = 0; mi < 4; mi++)
#pragma unroll
      for (int ni = 0; ni < 4; ni++)
#pragma unroll
        for (int j = 0; j < 4; j++) {
          int row = m0 + wr * 64 + mi * 16 + (lane >> 4) * 4 + j;
          int col = n0 + wc * 64 + ni * 16 + fr;
          O[(size_t)row * 1024 + col] = acc[mi][ni][j];
        }
    return;
  }

  __syncthreads();  // done with As/Bs staging area
#pragma unroll
  for (int mi = 0; mi < 4; mi++) {
    int r = wr * 64 + mi * 16 + (lane >> 4) * 4;
#pragma unroll
    for (int ni = 0; ni < 4; ni++) {
      int c = wc * 64 + ni * 16 + fr;
#pragma unroll
      for (int j = 0; j < 4; j++) Cs[r + j][c] = (bf16)acc[mi][ni][j];
    }
  }
  __syncthreads();

  bf16* O = (bf16*)outp;
  if (MODE == 0) {
    int row = tid >> 1, ch = (tid & 1) * 64;
    int rg = m0 + row;
    int b = rg >> 11, t_ = rg & 2047;
    int c0 = n0 + ch;
    int h = c0 >> 6;
    bf16* dst = O + ((size_t)(b * 16 + h) * 2048 + t_) * 64;
#pragma unroll
    for (int i = 0; i < 8; i++) *(bf16x8*)&dst[i * 8] = *(const bf16x8*)&Cs[row][ch + i * 8];
  } else {  // MODE 1: V^T
    int colL = tid >> 1, sh = (tid & 1) * 64;
    int cg = n0 + colL;
    int h = cg >> 6, d = cg & 63;
    int rg = m0 + sh;
    int b = rg >> 11, s_ = rg & 2047;
    bf16* dst = O + ((size_t)((b * 16 + h) * 64 + d)) * 2048 + s_;
#pragma unroll
    for (int i = 0; i < 8; i++) {
      bf16x8 v;
#pragma unroll
      for (int jj = 0; jj < 8; jj++) v[jj] = Cs[sh + i * 8 + jj][colL];
      *(bf16x8*)&dst[i * 8] = v;
    }
  }
}

// ---------------- flash attention (swapped QK^T, KVBLK=64) ----------------
// Q: [bh*2048 + t][64], K: [bh*2048 + s][64], Vt: [bh*64 + d][2048], Y: [b*2048+t][1024]
// Verified operand maps (from round-1 passing kernel):
//   A-frag: lane holds A[row=lane&15][k=(lane>>4)*8+reg]
//   B-frag: lane holds B[k=(lane>>4)*8+reg][col=lane&15]
//   C:      lane holds C[row=(lane>>4)*4+j][col=lane&15]
// QK^T swapped: mfma(A=K, B=Q) -> S^T[s][q]; lane's q = lane&15, s = 16h+(lane>>4)*4+j.
__global__ __launch_bounds__(256) void attn_kernel(const bf16* __restrict__ Q,
                                                   const bf16* __restrict__ Kc,
                                                   const bf16* __restrict__ Vt,
                                                   bf16* __restrict__ Y) {
  const int qt = blockIdx.x, bh = blockIdx.y;
  const int tid = threadIdx.x, lane = tid & 63, w = tid >> 6;
  const int lr = lane & 15, lg = lane >> 4;
  const int q0 = qt * 64 + w * 16;  // lane's q-row = q0 + lr
  __shared__ __align__(16) bf16 Plds[4][16][72];

  // Q fragments (B-operand): lane holds Q[q0+lr][d = lg*8+reg]
  const bf16* qb = Q + ((size_t)bh * 2048 + q0 + lr) * 64 + lg * 8;
  const bf16x8 qfB0 = *(const bf16x8*)qb;
  const bf16x8 qfB1 = *(const bf16x8*)(qb + 32);

  const bf16* Kbase = Kc + (size_t)bh * 2048 * 64;
  const bf16* Vbase = Vt + (size_t)bh * 64 * 2048;

  f32x4 yacc[4] = {};
  float mrow = -__builtin_inff(), lrow = 0.0f;
  const float SCL = 0.125f * 1.4426950408889634f;  // 1/sqrt(64) * log2(e)

  for (int c = 0; c <= qt; ++c) {
    const int sbase = c * 64;
    // K fragments (A-operand): lane holds K[sbase+16h+lr][d = lg*8+reg]
    bf16x8 kf0[4], kf1[4];
#pragma unroll
    for (int h = 0; h < 4; ++h) {
      const bf16* kp = Kbase + (size_t)(sbase + 16 * h + lr) * 64 + lg * 8;
      kf0[h] = *(const bf16x8*)kp;
      kf1[h] = *(const bf16x8*)(kp + 32);
    }
    // V fragments (B-operand for PV): lane holds V[s = sbase+sh*32+lg*8+reg][d = nf*16+lr]
    bf16x8 vf[4][2];
#pragma unroll
    for (int nf = 0; nf < 4; ++nf)
#pragma unroll
      for (int sh = 0; sh < 2; ++sh)
        vf[nf][sh] =
            *(const bf16x8*)(Vbase + (size_t)(nf * 16 + lr) * 2048 + sbase + sh * 32 + lg * 8);

    // S^T = K . Q^T  (16 q-cols, 64 s-rows)
    f32x4 st[4];
#pragma unroll
    for (int h = 0; h < 4; ++h) {
      f32x4 z = {};
      z = __builtin_amdgcn_mfma_f32_16x16x32_bf16(kf0[h], qfB0, z, 0, 0, 0);
      z = __builtin_amdgcn_mfma_f32_16x16x32_bf16(kf1[h], qfB1, z, 0, 0, 0);
      st[h] = z;
    }
    // scale into log2 domain; mask only on the diagonal chunk (wave-uniform branch)
#pragma unroll
    for (int h = 0; h < 4; ++h)
#pragma unroll
      for (int j = 0; j < 4; ++j) st[h][j] *= SCL;
    if (c == qt) {
      const int qg = q0 + lr;
#pragma unroll
      for (int h = 0; h < 4; ++h)
#pragma unroll
        for (int j = 0; j < 4; ++j) {
          int sg = sbase + 16 * h + lg * 4 + j;
          if (sg > qg) st[h][j] = -__builtin_inff();
        }
    }
    // row stats: in-lane over 16 regs, then 2 shfls across lg groups
    float vmax = fmaxf(fmaxf(st[0][0], st[0][1]), fmaxf(st[0][2], st[0][3]));
#pragma unroll
    for (int h = 1; h < 4; ++h)
      vmax = fmaxf(vmax, fmaxf(fmaxf(st[h][0], st[h][1]), fmaxf(st[h][2], st[h][3])));
    vmax = fmaxf(vmax, __shfl_xor(vmax, 16));
    vmax = fmaxf(vmax, __shfl_xor(vmax, 32));
    const float mnew = fmaxf(mrow, vmax);
    const float cf = EXP2F(mrow - mnew);
    mrow = mnew;

    float rs = 0.0f;
#pragma unroll
    for (int h = 0; h < 4; ++h) {
      float p0 = EXP2F(st[h][0] - mnew);
      float p1 = EXP2F(st[h][1] - mnew);
      float p2 = EXP2F(st[h][2] - mnew);
      float p3 = EXP2F(st[h][3] - mnew);
      rs += (p0 + p1) + (p2 + p3);
      bf16x4 pk = {(bf16)p0, (bf16)p1, (bf16)p2, (bf16)p3};
      *(bf16x4*)&Plds[w][lr][16 * h + lg * 4] = pk;  // P[q=lr][s=16h+lg*4 ..]
    }
    rs += __shfl_xor(rs, 16);
    rs += __shfl_xor(rs, 32);
    lrow = lrow * cf + rs;

    // rescale yacc (its q-row is lg*4+j -> broadcast cf from lane lg*4+j)
    float cfj[4];
#pragma unroll
    for (int j = 0; j < 4; ++j) cfj[j] = __shfl(cf, lg * 4 + j);
#pragma unroll
    for (int nf = 0; nf < 4; ++nf)
#pragma unroll
      for (int j = 0; j < 4; ++j) yacc[nf][j] *= cfj[j];

    // PV: A = P[q][s] from LDS, B = V
    const bf16x8 pa0 = *(const bf16x8*)&Plds[w][lr][lg * 8];
    const bf16x8 pa1 = *(const bf16x8*)&Plds[w][lr][32 + lg * 8];
#pragma unroll
    for (int nf = 0; nf < 4; ++nf) {
      yacc[nf] = __builtin_amdgcn_mfma_f32_16x16x32_bf16(pa0, vf[nf][0], yacc[nf], 0, 0, 0);
      yacc[nf] = __builtin_amdgcn_mfma_f32_16x16x32_bf16(pa1, vf[nf][1], yacc[nf], 0, 0, 0);
    }
  }

  const float rinv = 1.0f / lrow;
  float linv[4];
#pragma unroll
  for (int j = 0; j < 4; ++j) linv[j] = __shfl(rinv, lg * 4 + j);
  const int b = bh >> 4, h = bh & 15;
#pragma unroll
  for (int nf = 0; nf < 4; ++nf)
#pragma unroll
    for (int j = 0; j < 4; ++j) {
      int qg = q0 + lg * 4 + j;
      Y[((size_t)b * 2048 + qg) * 1024 + h * 64 + nf * 16 + lr] = (bf16)(yacc[nf][j] * linv[j]);
    }
}

extern "C" void kernel_launch(void* const* d_in, const int* in_sizes, int n_in,
                              void* d_out, int out_size, void* d_ws, size_t ws_size,
                              hipStream_t stream) {
  const float* x = (const float*)d_in[0];
  const float* ctx = (const float*)d_in[1];
  const float* q_w = (const float*)d_in[2];
  const float* q_b = (const float*)d_in[3];
  const float* k_w = (const float*)d_in[4];
  const float* k_b = (const float*)d_in[5];
  const float* v_w = (const float*)d_in[6];
  const float* v_b = (const float*)d_in[7];
  const float* o_w = (const float*)d_in[8];
  const float* o_b = (const float*)d_in[9];

  char* ws = (char*)d_ws;
  const size_t MB = 1024 * 1024;
  bf16* xb = (bf16*)(ws + 0);
  bf16* cb = (bf16*)(ws + 8 * MB);
  bf16* qwt = (bf16*)(ws + 16 * MB);
  bf16* kwt = (bf16*)(ws + 18 * MB);
  bf16* vwt = (bf16*)(ws + 20 * MB);
  bf16* owt = (bf16*)(ws + 22 * MB);
  bf16* Qws = (bf16*)(ws + 24 * MB);
  bf16* Kws = (bf16*)(ws + 32 * MB);
  bf16* Vt = (bf16*)(ws + 40 * MB);
  bf16* Yws = (bf16*)(ws + 48 * MB);

  cvt_kernel<<<4096, 256, 0, stream>>>((const float4*)x, (bf16x4*)xb, 1048576);
  cvt_kernel<<<4096, 256, 0, stream>>>((const float4*)ctx, (bf16x4*)cb, 1048576);

  dim3 tb(32, 8), tg(32, 32);
  transpose_kernel<<<tg, tb, 0, stream>>>(q_w, qwt);
  transpose_kernel<<<tg, tb, 0, stream>>>(k_w, kwt);
  transpose_kernel<<<tg, tb, 0, stream>>>(v_w, vwt);
  transpose_kernel<<<tg, tb, 0, stream>>>(o_w, owt);

  dim3 gg(8, 32);
  gemm_kernel<0><<<gg, 256, 0, stream>>>(xb, qwt, q_b, (void*)Qws);
  gemm_kernel<0><<<gg, 256, 0, stream>>>(cb, kwt, k_b, (void*)Kws);
  gemm_kernel<1><<<gg, 256, 0, stream>>>(cb, vwt, v_b, (void*)Vt);

  attn_kernel<<<dim3(32, 32), 256, 0, stream>>>(Qws, Kws, Vt, Yws);

  gemm_kernel<2><<<gg, 256, 0, stream>>>(Yws, owt, o_b, d_out);
}

// Round 3
// 152.957 us; speedup vs baseline: 2.4325x; 2.4325x over previous
//
#include <hip/hip_runtime.h>
#include <hip/hip_bf16.h>

using bf16 = __bf16;
using bf16x4 = __attribute__((ext_vector_type(4))) __bf16;
using bf16x8 = __attribute__((ext_vector_type(8))) __bf16;
using f32x4 = __attribute__((ext_vector_type(4))) float;

#define EXP2F(x) __builtin_amdgcn_exp2f(x)

// ---------------- prep: fp32 -> bf16 elementwise ----------------
__global__ __launch_bounds__(256) void cvt_kernel(const float4* __restrict__ in,
                                                  bf16x4* __restrict__ out, int n4) {
  int g = blockIdx.x * blockDim.x + threadIdx.x;
  if (g < n4) {
    float4 v = in[g];
    bf16x4 o = {(bf16)v.x, (bf16)v.y, (bf16)v.z, (bf16)v.w};
    out[g] = o;
  }
}

// ---------------- prep: W[k][n] fp32 -> Wt[n][k] bf16 ----------------
__global__ __launch_bounds__(256) void transpose_kernel(const float* __restrict__ w,
                                                        bf16* __restrict__ wt) {
  __shared__ float tile[32][33];
  int k0 = blockIdx.y * 32, n0 = blockIdx.x * 32;
  int tx = threadIdx.x, ty = threadIdx.y;
#pragma unroll
  for (int i = 0; i < 4; i++)
    tile[ty + i * 8][tx] = w[(size_t)(k0 + ty + i * 8) * 1024 + n0 + tx];
  __syncthreads();
#pragma unroll
  for (int i = 0; i < 4; i++)
    wt[(size_t)(n0 + ty + i * 8) * 1024 + k0 + tx] = (bf16)tile[tx][ty + i * 8];
}

// ---------------- GEMM: C[m][n] = A[m][k] * Wt[n][k]^T + bias ----------------
// (unchanged from round 2)
template <int MODE>
__global__ __launch_bounds__(256) void gemm_kernel(const bf16* __restrict__ A,
                                                   const bf16* __restrict__ Bt,
                                                   const float* __restrict__ bias,
                                                   void* __restrict__ outp) {
  constexpr int K = 1024;
  __shared__ __align__(16) char smem[34816];
  bf16(*As)[40] = (bf16(*)[40])smem;
  bf16(*Bs)[40] = (bf16(*)[40])(smem + 10240);
  bf16(*Cs)[136] = (bf16(*)[136])smem;

  const int tid = threadIdx.x;
  const int lane = tid & 63;
  const int w = tid >> 6;
  const int wr = w >> 1, wc = w & 1;
  const int m0 = blockIdx.y * 128, n0 = blockIdx.x * 128;
  const int fr = lane & 15, fg = (lane >> 4) * 8;

  f32x4 acc[4][4] = {};

  const int srow = tid >> 2;             // 0..63
  const int kc = (tid & 3) * 8;          // 0,8,16,24
  const int arow = m0 + srow, brow = n0 + srow;

  bf16x8 ra0, ra1, rb0, rb1;
  ra0 = *(const bf16x8*)&A[(size_t)arow * K + kc];
  ra1 = *(const bf16x8*)&A[(size_t)(arow + 64) * K + kc];
  rb0 = *(const bf16x8*)&Bt[(size_t)brow * K + kc];
  rb1 = *(const bf16x8*)&Bt[(size_t)(brow + 64) * K + kc];

  for (int k0 = 0; k0 < K; k0 += 32) {
    __syncthreads();
    *(bf16x8*)&As[srow][kc] = ra0;
    *(bf16x8*)&As[srow + 64][kc] = ra1;
    *(bf16x8*)&Bs[srow][kc] = rb0;
    *(bf16x8*)&Bs[srow + 64][kc] = rb1;
    if (k0 + 32 < K) {
      int kn = k0 + 32 + kc;
      ra0 = *(const bf16x8*)&A[(size_t)arow * K + kn];
      ra1 = *(const bf16x8*)&A[(size_t)(arow + 64) * K + kn];
      rb0 = *(const bf16x8*)&Bt[(size_t)brow * K + kn];
      rb1 = *(const bf16x8*)&Bt[(size_t)(brow + 64) * K + kn];
    }
    __syncthreads();
    bf16x8 af[4], bfr[4];
#pragma unroll
    for (int mi = 0; mi < 4; mi++)
      af[mi] = *(const bf16x8*)&As[wr * 64 + mi * 16 + fr][fg];
#pragma unroll
    for (int ni = 0; ni < 4; ni++)
      bfr[ni] = *(const bf16x8*)&Bs[wc * 64 + ni * 16 + fr][fg];
#pragma unroll
    for (int mi = 0; mi < 4; mi++)
#pragma unroll
      for (int ni = 0; ni < 4; ni++)
        acc[mi][ni] =
            __builtin_amdgcn_mfma_f32_16x16x32_bf16(af[mi], bfr[ni], acc[mi][ni], 0, 0, 0);
  }

  float bv[4];
#pragma unroll
  for (int ni = 0; ni < 4; ni++) bv[ni] = bias[n0 + wc * 64 + ni * 16 + fr];
#pragma unroll
  for (int mi = 0; mi < 4; mi++)
#pragma unroll
    for (int ni = 0; ni < 4; ni++)
#pragma unroll
      for (int j = 0; j < 4; j++) acc[mi][ni][j] += bv[ni];

  if (MODE == 2) {
    float* O = (float*)outp;
#pragma unroll
    for (int mi = 0; mi < 4; mi++)
#pragma unroll
      for (int ni = 0; ni < 4; ni++)
#pragma unroll
        for (int j = 0; j < 4; j++) {
          int row = m0 + wr * 64 + mi * 16 + (lane >> 4) * 4 + j;
          int col = n0 + wc * 64 + ni * 16 + fr;
          O[(size_t)row * 1024 + col] = acc[mi][ni][j];
        }
    return;
  }

  __syncthreads();
#pragma unroll
  for (int mi = 0; mi < 4; mi++) {
    int r = wr * 64 + mi * 16 + (lane >> 4) * 4;
#pragma unroll
    for (int ni = 0; ni < 4; ni++) {
      int c = wc * 64 + ni * 16 + fr;
#pragma unroll
      for (int j = 0; j < 4; j++) Cs[r + j][c] = (bf16)acc[mi][ni][j];
    }
  }
  __syncthreads();

  bf16* O = (bf16*)outp;
  if (MODE == 0) {
    int row = tid >> 1, ch = (tid & 1) * 64;
    int rg = m0 + row;
    int b = rg >> 11, t_ = rg & 2047;
    int c0 = n0 + ch;
    int h = c0 >> 6;
    bf16* dst = O + ((size_t)(b * 16 + h) * 2048 + t_) * 64;
#pragma unroll
    for (int i = 0; i < 8; i++) *(bf16x8*)&dst[i * 8] = *(const bf16x8*)&Cs[row][ch + i * 8];
  } else {  // MODE 1: V^T
    int colL = tid >> 1, sh = (tid & 1) * 64;
    int cg = n0 + colL;
    int h = cg >> 6, d = cg & 63;
    int rg = m0 + sh;
    int b = rg >> 11, s_ = rg & 2047;
    bf16* dst = O + ((size_t)((b * 16 + h) * 64 + d)) * 2048 + s_;
#pragma unroll
    for (int i = 0; i < 8; i++) {
      bf16x8 v;
#pragma unroll
      for (int jj = 0; jj < 8; jj++) v[jj] = Cs[sh + i * 8 + jj][colL];
      *(bf16x8*)&dst[i * 8] = v;
    }
  }
}

// ---------------- flash attention (LDS-shared K/V, swizzled, prefetch) ----------------
// Q: [bh*2048 + t][64], K: [bh*2048 + s][64], Vt: [bh*64 + d][2048], Y: [b*2048+t][1024]
// grid: x = bh (XCD locality: lin%8 = bh%8), y: qt = 31-y (longest first)
// LDS tiles [64 rows][64 elems], XOR-swizzled: elem_col ^= (row&7)*8  (16B granules)
__global__ __launch_bounds__(256) void attn_kernel(const bf16* __restrict__ Q,
                                                   const bf16* __restrict__ Kc,
                                                   const bf16* __restrict__ Vt,
                                                   bf16* __restrict__ Y) {
  const int bh = blockIdx.x;
  const int qt = 31 - blockIdx.y;
  const int tid = threadIdx.x, lane = tid & 63, w = tid >> 6;
  const int lr = lane & 15, lg = lane >> 4;
  const int q0 = qt * 64 + w * 16;  // lane's q-row = q0 + lr

  __shared__ __align__(16) bf16 Ks[64 * 64];
  __shared__ __align__(16) bf16 Vs[64 * 64];
  __shared__ __align__(16) bf16 Plds[4][16][72];

  // Q fragments (B-operand): lane holds Q[q0+lr][d = lg*8+reg]
  const bf16* qb = Q + ((size_t)bh * 2048 + q0 + lr) * 64 + lg * 8;
  const bf16x8 qfB0 = *(const bf16x8*)qb;
  const bf16x8 qfB1 = *(const bf16x8*)(qb + 32);

  const bf16* Kbase = Kc + (size_t)bh * 2048 * 64;
  const bf16* Vbase = Vt + (size_t)bh * 64 * 2048;

  // staging coords: thread covers 32B of one row (global-contiguous per 4 lanes)
  const int srow = tid >> 2;          // 0..63  (K: s-local row; V: d row)
  const int scol = (tid & 3) * 16;    // element col 0,16,32,48
  const int r7x = (srow & 7) * 8;     // swizzle XOR in elements (16B granule)
  const int d0 = srow * 64 + (scol ^ r7x);
  const int d1 = srow * 64 + ((scol + 8) ^ r7x);

  // prologue prefetch (chunk 0)
  bf16x8 kr0, kr1, vr0, vr1;
  {
    const bf16* kp = Kbase + (size_t)srow * 64 + scol;
    kr0 = *(const bf16x8*)kp;
    kr1 = *(const bf16x8*)(kp + 8);
    const bf16* vp = Vbase + (size_t)srow * 2048 + scol;
    vr0 = *(const bf16x8*)vp;
    vr1 = *(const bf16x8*)(vp + 8);
  }

  f32x4 yacc[4] = {};
  float mrow = -__builtin_inff(), lrow = 0.0f;
  const float SCL = 0.125f * 1.4426950408889634f;  // 1/sqrt(64) * log2(e)
  const int kxor = (lr & 7) * 8;

  for (int c = 0; c <= qt; ++c) {
    const int sbase = c * 64;
    __syncthreads();  // all waves done reading previous tiles
    *(bf16x8*)&Ks[d0] = kr0;
    *(bf16x8*)&Ks[d1] = kr1;
    *(bf16x8*)&Vs[d0] = vr0;
    *(bf16x8*)&Vs[d1] = vr1;
    __syncthreads();  // tiles ready

    // prefetch next chunk into regs (hidden under compute)
    {
      const int cn = (c < qt) ? c + 1 : c;
      const int sb = cn * 64;
      const bf16* kp = Kbase + (size_t)(sb + srow) * 64 + scol;
      kr0 = *(const bf16x8*)kp;
      kr1 = *(const bf16x8*)(kp + 8);
      const bf16* vp = Vbase + (size_t)srow * 2048 + sb + scol;
      vr0 = *(const bf16x8*)vp;
      vr1 = *(const bf16x8*)(vp + 8);
    }

    // S^T = K . Q^T  (A-frag from swizzled Ks)
    f32x4 st[4];
#pragma unroll
    for (int h = 0; h < 4; ++h) {
      const int rb = (16 * h + lr) * 64;
      const bf16x8 kf0 = *(const bf16x8*)&Ks[rb + ((lg * 8) ^ kxor)];
      const bf16x8 kf1 = *(const bf16x8*)&Ks[rb + ((32 + lg * 8) ^ kxor)];
      f32x4 z = {};
      z = __builtin_amdgcn_mfma_f32_16x16x32_bf16(kf0, qfB0, z, 0, 0, 0);
      z = __builtin_amdgcn_mfma_f32_16x16x32_bf16(kf1, qfB1, z, 0, 0, 0);
      st[h] = z;
    }
#pragma unroll
    for (int h = 0; h < 4; ++h)
#pragma unroll
      for (int j = 0; j < 4; ++j) st[h][j] *= SCL;
    if (c == qt) {  // diagonal chunk: causal mask
      const int qg = q0 + lr;
#pragma unroll
      for (int h = 0; h < 4; ++h)
#pragma unroll
        for (int j = 0; j < 4; ++j) {
          int sg = sbase + 16 * h + lg * 4 + j;
          if (sg > qg) st[h][j] = -__builtin_inff();
        }
    }
    // row stats: in-lane over 16 regs + 2 shfls
    float vmax = fmaxf(fmaxf(st[0][0], st[0][1]), fmaxf(st[0][2], st[0][3]));
#pragma unroll
    for (int h = 1; h < 4; ++h)
      vmax = fmaxf(vmax, fmaxf(fmaxf(st[h][0], st[h][1]), fmaxf(st[h][2], st[h][3])));
    vmax = fmaxf(vmax, __shfl_xor(vmax, 16));
    vmax = fmaxf(vmax, __shfl_xor(vmax, 32));
    const float mnew = fmaxf(mrow, vmax);
    const float cf = EXP2F(mrow - mnew);
    mrow = mnew;

    float rs = 0.0f;
#pragma unroll
    for (int h = 0; h < 4; ++h) {
      float p0 = EXP2F(st[h][0] - mnew);
      float p1 = EXP2F(st[h][1] - mnew);
      float p2 = EXP2F(st[h][2] - mnew);
      float p3 = EXP2F(st[h][3] - mnew);
      rs += (p0 + p1) + (p2 + p3);
      bf16x4 pk = {(bf16)p0, (bf16)p1, (bf16)p2, (bf16)p3};
      *(bf16x4*)&Plds[w][lr][16 * h + lg * 4] = pk;  // P[q=lr][s=16h+lg*4..]
    }
    rs += __shfl_xor(rs, 16);
    rs += __shfl_xor(rs, 32);
    lrow = lrow * cf + rs;

    // rescale yacc (its q-row is lg*4+j)
    float cfj[4];
#pragma unroll
    for (int j = 0; j < 4; ++j) cfj[j] = __shfl(cf, lg * 4 + j);
#pragma unroll
    for (int nf = 0; nf < 4; ++nf)
#pragma unroll
      for (int j = 0; j < 4; ++j) yacc[nf][j] *= cfj[j];

    // PV: A = P (from Plds), B = V (from swizzled Vs)
    const bf16x8 pa0 = *(const bf16x8*)&Plds[w][lr][lg * 8];
    const bf16x8 pa1 = *(const bf16x8*)&Plds[w][lr][32 + lg * 8];
#pragma unroll
    for (int nf = 0; nf < 4; ++nf) {
      const int rb = (nf * 16 + lr) * 64;
      const bf16x8 vf0 = *(const bf16x8*)&Vs[rb + ((lg * 8) ^ kxor)];
      const bf16x8 vf1 = *(const bf16x8*)&Vs[rb + ((32 + lg * 8) ^ kxor)];
      yacc[nf] = __builtin_amdgcn_mfma_f32_16x16x32_bf16(pa0, vf0, yacc[nf], 0, 0, 0);
      yacc[nf] = __builtin_amdgcn_mfma_f32_16x16x32_bf16(pa1, vf1, yacc[nf], 0, 0, 0);
    }
  }

  const float rinv = 1.0f / lrow;
  float linv[4];
#pragma unroll
  for (int j = 0; j < 4; ++j) linv[j] = __shfl(rinv, lg * 4 + j);
  const int b = bh >> 4, h = bh & 15;
#pragma unroll
  for (int nf = 0; nf < 4; ++nf)
#pragma unroll
    for (int j = 0; j < 4; ++j) {
      int qg = q0 + lg * 4 + j;
      Y[((size_t)b * 2048 + qg) * 1024 + h * 64 + nf * 16 + lr] = (bf16)(yacc[nf][j] * linv[j]);
    }
}

extern "C" void kernel_launch(void* const* d_in, const int* in_sizes, int n_in,
                              void* d_out, int out_size, void* d_ws, size_t ws_size,
                              hipStream_t stream) {
  const float* x = (const float*)d_in[0];
  const float* ctx = (const float*)d_in[1];
  const float* q_w = (const float*)d_in[2];
  const float* q_b = (const float*)d_in[3];
  const float* k_w = (const float*)d_in[4];
  const float* k_b = (const float*)d_in[5];
  const float* v_w = (const float*)d_in[6];
  const float* v_b = (const float*)d_in[7];
  const float* o_w = (const float*)d_in[8];
  const float* o_b = (const float*)d_in[9];

  char* ws = (char*)d_ws;
  const size_t MB = 1024 * 1024;
  bf16* xb = (bf16*)(ws + 0);
  bf16* cb = (bf16*)(ws + 8 * MB);
  bf16* qwt = (bf16*)(ws + 16 * MB);
  bf16* kwt = (bf16*)(ws + 18 * MB);
  bf16* vwt = (bf16*)(ws + 20 * MB);
  bf16* owt = (bf16*)(ws + 22 * MB);
  bf16* Qws = (bf16*)(ws + 24 * MB);
  bf16* Kws = (bf16*)(ws + 32 * MB);
  bf16* Vt = (bf16*)(ws + 40 * MB);
  bf16* Yws = (bf16*)(ws + 48 * MB);

  cvt_kernel<<<4096, 256, 0, stream>>>((const float4*)x, (bf16x4*)xb, 1048576);
  cvt_kernel<<<4096, 256, 0, stream>>>((const float4*)ctx, (bf16x4*)cb, 1048576);

  dim3 tb(32, 8), tg(32, 32);
  transpose_kernel<<<tg, tb, 0, stream>>>(q_w, qwt);
  transpose_kernel<<<tg, tb, 0, stream>>>(k_w, kwt);
  transpose_kernel<<<tg, tb, 0, stream>>>(v_w, vwt);
  transpose_kernel<<<tg, tb, 0, stream>>>(o_w, owt);

  dim3 gg(8, 32);
  gemm_kernel<0><<<gg, 256, 0, stream>>>(xb, qwt, q_b, (void*)Qws);
  gemm_kernel<0><<<gg, 256, 0, stream>>>(cb, kwt, k_b, (void*)Kws);
  gemm_kernel<1><<<gg, 256, 0, stream>>>(cb, vwt, v_b, (void*)Vt);

  attn_kernel<<<dim3(32, 32), 256, 0, stream>>>(Qws, Kws, Vt, Yws);

  gemm_kernel<2><<<gg, 256, 0, stream>>>(Yws, owt, o_b, d_out);
}

// Round 4
// 127.121 us; speedup vs baseline: 2.9268x; 1.2032x over previous
//
#include <hip/hip_runtime.h>
#include <hip/hip_bf16.h>

using bf16 = __bf16;
using bf16x4 = __attribute__((ext_vector_type(4))) __bf16;
using bf16x8 = __attribute__((ext_vector_type(8))) __bf16;
using f32x4 = __attribute__((ext_vector_type(4))) float;

#define EXP2F(x) __builtin_amdgcn_exp2f(x)

// ---------------- prep: fp32 -> bf16 (x and ctx in one launch; outputs contiguous) ----------------
__global__ __launch_bounds__(256) void cvt_kernel(const float4* __restrict__ a,
                                                  const float4* __restrict__ b,
                                                  bf16x4* __restrict__ out) {
  int g = blockIdx.x * blockDim.x + threadIdx.x;  // 0 .. 2*1048576-1
  float4 v = (g < 1048576) ? a[g] : b[g - 1048576];
  bf16x4 o = {(bf16)v.x, (bf16)v.y, (bf16)v.z, (bf16)v.w};
  out[g] = o;
}

// ---------------- prep: all 4 weights W[k][n] fp32 -> Wt[n][k] bf16, one launch ----------------
__global__ __launch_bounds__(256) void transpose_kernel(const float* __restrict__ w0,
                                                        const float* __restrict__ w1,
                                                        const float* __restrict__ w2,
                                                        const float* __restrict__ w3,
                                                        bf16* __restrict__ wtbase) {
  __shared__ float tile[32][33];
  const int z = blockIdx.z;
  const float* w = (z == 0) ? w0 : (z == 1) ? w1 : (z == 2) ? w2 : w3;
  bf16* wt = wtbase + (size_t)z * 1048576;
  int k0 = blockIdx.y * 32, n0 = blockIdx.x * 32;
  int tx = threadIdx.x, ty = threadIdx.y;
#pragma unroll
  for (int i = 0; i < 4; i++)
    tile[ty + i * 8][tx] = w[(size_t)(k0 + ty + i * 8) * 1024 + n0 + tx];
  __syncthreads();
#pragma unroll
  for (int i = 0; i < 4; i++)
    wt[(size_t)(n0 + ty + i * 8) * 1024 + k0 + tx] = (bf16)tile[tx][ty + i * 8];
}

// ---------------- GEMM core ----------------
// C[m][n] = A[m][k] * Wt[n][k]^T + bias
// mode 0: out bf16, head-split [(b*16+h)*2048 + t][64]
// mode 1: out bf16, V-transposed [((b*16+h)*64 + d)][2048]
// mode 2: out fp32, plain [m][1024]
__device__ __forceinline__ void gemm_body(const bf16* __restrict__ A,
                                          const bf16* __restrict__ Bt,
                                          const float* __restrict__ bias,
                                          void* __restrict__ outp, int mode, int bx, int by) {
  constexpr int K = 1024;
  __shared__ __align__(16) char smem[34816];
  bf16(*As)[40] = (bf16(*)[40])smem;
  bf16(*Bs)[40] = (bf16(*)[40])(smem + 10240);
  bf16(*Cs)[136] = (bf16(*)[136])smem;

  const int tid = threadIdx.x;
  const int lane = tid & 63;
  const int w = tid >> 6;
  const int wr = w >> 1, wc = w & 1;
  const int m0 = by * 128, n0 = bx * 128;
  const int fr = lane & 15, fg = (lane >> 4) * 8;

  f32x4 acc[4][4] = {};

  const int srow = tid >> 2;
  const int kc = (tid & 3) * 8;
  const int arow = m0 + srow, brow = n0 + srow;

  bf16x8 ra0, ra1, rb0, rb1;
  ra0 = *(const bf16x8*)&A[(size_t)arow * K + kc];
  ra1 = *(const bf16x8*)&A[(size_t)(arow + 64) * K + kc];
  rb0 = *(const bf16x8*)&Bt[(size_t)brow * K + kc];
  rb1 = *(const bf16x8*)&Bt[(size_t)(brow + 64) * K + kc];

  for (int k0 = 0; k0 < K; k0 += 32) {
    __syncthreads();
    *(bf16x8*)&As[srow][kc] = ra0;
    *(bf16x8*)&As[srow + 64][kc] = ra1;
    *(bf16x8*)&Bs[srow][kc] = rb0;
    *(bf16x8*)&Bs[srow + 64][kc] = rb1;
    if (k0 + 32 < K) {
      int kn = k0 + 32 + kc;
      ra0 = *(const bf16x8*)&A[(size_t)arow * K + kn];
      ra1 = *(const bf16x8*)&A[(size_t)(arow + 64) * K + kn];
      rb0 = *(const bf16x8*)&Bt[(size_t)brow * K + kn];
      rb1 = *(const bf16x8*)&Bt[(size_t)(brow + 64) * K + kn];
    }
    __syncthreads();
    bf16x8 af[4], bfr[4];
#pragma unroll
    for (int mi = 0; mi < 4; mi++)
      af[mi] = *(const bf16x8*)&As[wr * 64 + mi * 16 + fr][fg];
#pragma unroll
    for (int ni = 0; ni < 4; ni++)
      bfr[ni] = *(const bf16x8*)&Bs[wc * 64 + ni * 16 + fr][fg];
#pragma unroll
    for (int mi = 0; mi < 4; mi++)
#pragma unroll
      for (int ni = 0; ni < 4; ni++)
        acc[mi][ni] =
            __builtin_amdgcn_mfma_f32_16x16x32_bf16(af[mi], bfr[ni], acc[mi][ni], 0, 0, 0);
  }

  float bv[4];
#pragma unroll
  for (int ni = 0; ni < 4; ni++) bv[ni] = bias[n0 + wc * 64 + ni * 16 + fr];
#pragma unroll
  for (int mi = 0; mi < 4; mi++)
#pragma unroll
    for (int ni = 0; ni < 4; ni++)
#pragma unroll
      for (int j = 0; j < 4; j++) acc[mi][ni][j] += bv[ni];

  if (mode == 2) {
    float* O = (float*)outp;
#pragma unroll
    for (int mi = 0; mi < 4; mi++)
#pragma unroll
      for (int ni = 0; ni < 4; ni++)
#pragma unroll
        for (int j = 0; j < 4; j++) {
          int row = m0 + wr * 64 + mi * 16 + (lane >> 4) * 4 + j;
          int col = n0 + wc * 64 + ni * 16 + fr;
          O[(size_t)row * 1024 + col] = acc[mi][ni][j];
        }
    return;
  }

  __syncthreads();
#pragma unroll
  for (int mi = 0; mi < 4; mi++) {
    int r = wr * 64 + mi * 16 + (lane >> 4) * 4;
#pragma unroll
    for (int ni = 0; ni < 4; ni++) {
      int c = wc * 64 + ni * 16 + fr;
#pragma unroll
      for (int j = 0; j < 4; j++) Cs[r + j][c] = (bf16)acc[mi][ni][j];
    }
  }
  __syncthreads();

  bf16* O = (bf16*)outp;
  if (mode == 0) {
    int row = tid >> 1, ch = (tid & 1) * 64;
    int rg = m0 + row;
    int b = rg >> 11, t_ = rg & 2047;
    int c0 = n0 + ch;
    int h = c0 >> 6;
    bf16* dst = O + ((size_t)(b * 16 + h) * 2048 + t_) * 64;
#pragma unroll
    for (int i = 0; i < 8; i++) *(bf16x8*)&dst[i * 8] = *(const bf16x8*)&Cs[row][ch + i * 8];
  } else {  // mode 1: V^T
    int colL = tid >> 1, sh = (tid & 1) * 64;
    int cg = n0 + colL;
    int h = cg >> 6, d = cg & 63;
    int rg = m0 + sh;
    int b = rg >> 11, s_ = rg & 2047;
    bf16* dst = O + ((size_t)((b * 16 + h) * 64 + d)) * 2048 + s_;
#pragma unroll
    for (int i = 0; i < 8; i++) {
      bf16x8 v;
#pragma unroll
      for (int jj = 0; jj < 8; jj++) v[jj] = Cs[sh + i * 8 + jj][colL];
      *(bf16x8*)&dst[i * 8] = v;
    }
  }
}

// merged Q/K/V projection GEMMs: z=0 -> Q (A=xb), z=1 -> K (A=cb), z=2 -> V^T (A=cb)
__global__ __launch_bounds__(256) void gemm_qkv_kernel(const bf16* __restrict__ xb,
                                                       const bf16* __restrict__ cb,
                                                       const bf16* __restrict__ wtbase,
                                                       const float* __restrict__ bq,
                                                       const float* __restrict__ bk,
                                                       const float* __restrict__ bv,
                                                       bf16* __restrict__ outbase) {
  const int z = blockIdx.z;
  const bf16* A = (z == 0) ? xb : cb;
  const bf16* Wt = wtbase + (size_t)z * 1048576;
  const float* bias = (z == 0) ? bq : (z == 1) ? bk : bv;
  bf16* out = outbase + (size_t)z * 4194304;
  gemm_body(A, Wt, bias, (void*)out, (z == 2) ? 1 : 0, blockIdx.x, blockIdx.y);
}

// output projection GEMM (fp32 out)
__global__ __launch_bounds__(256) void gemm_o_kernel(const bf16* __restrict__ A,
                                                     const bf16* __restrict__ Wt,
                                                     const float* __restrict__ bias,
                                                     float* __restrict__ out) {
  gemm_body(A, Wt, bias, (void*)out, 2, blockIdx.x, blockIdx.y);
}

// ---------------- flash attention (LDS-shared K/V, swizzled, prefetch, defer-max) ----------------
__global__ __launch_bounds__(256) void attn_kernel(const bf16* __restrict__ Q,
                                                   const bf16* __restrict__ Kc,
                                                   const bf16* __restrict__ Vt,
                                                   bf16* __restrict__ Y) {
  const int bh = blockIdx.x;
  const int qt = 31 - blockIdx.y;
  const int tid = threadIdx.x, lane = tid & 63, w = tid >> 6;
  const int lr = lane & 15, lg = lane >> 4;
  const int q0 = qt * 64 + w * 16;  // lane's q-row = q0 + lr

  __shared__ __align__(16) bf16 Ks[64 * 64];
  __shared__ __align__(16) bf16 Vs[64 * 64];
  __shared__ __align__(16) bf16 Plds[4][16][72];

  const bf16* qb = Q + ((size_t)bh * 2048 + q0 + lr) * 64 + lg * 8;
  const bf16x8 qfB0 = *(const bf16x8*)qb;
  const bf16x8 qfB1 = *(const bf16x8*)(qb + 32);

  const bf16* Kbase = Kc + (size_t)bh * 2048 * 64;
  const bf16* Vbase = Vt + (size_t)bh * 64 * 2048;

  const int srow = tid >> 2;
  const int scol = (tid & 3) * 16;
  const int r7x = (srow & 7) * 8;
  const int d0 = srow * 64 + (scol ^ r7x);
  const int d1 = srow * 64 + ((scol + 8) ^ r7x);

  bf16x8 kr0, kr1, vr0, vr1;
  {
    const bf16* kp = Kbase + (size_t)srow * 64 + scol;
    kr0 = *(const bf16x8*)kp;
    kr1 = *(const bf16x8*)(kp + 8);
    const bf16* vp = Vbase + (size_t)srow * 2048 + scol;
    vr0 = *(const bf16x8*)vp;
    vr1 = *(const bf16x8*)(vp + 8);
  }

  f32x4 yacc[4] = {};
  float mrow = -__builtin_inff(), lrow = 0.0f;
  const float SCL = 0.125f * 1.4426950408889634f;
  const int kxor = (lr & 7) * 8;

  for (int c = 0; c <= qt; ++c) {
    const int sbase = c * 64;
    __syncthreads();
    *(bf16x8*)&Ks[d0] = kr0;
    *(bf16x8*)&Ks[d1] = kr1;
    *(bf16x8*)&Vs[d0] = vr0;
    *(bf16x8*)&Vs[d1] = vr1;
    __syncthreads();

    {
      const int cn = (c < qt) ? c + 1 : c;
      const int sb = cn * 64;
      const bf16* kp = Kbase + (size_t)(sb + srow) * 64 + scol;
      kr0 = *(const bf16x8*)kp;
      kr1 = *(const bf16x8*)(kp + 8);
      const bf16* vp = Vbase + (size_t)srow * 2048 + sb + scol;
      vr0 = *(const bf16x8*)vp;
      vr1 = *(const bf16x8*)(vp + 8);
    }

    f32x4 st[4];
#pragma unroll
    for (int h = 0; h < 4; ++h) {
      const int rb = (16 * h + lr) * 64;
      const bf16x8 kf0 = *(const bf16x8*)&Ks[rb + ((lg * 8) ^ kxor)];
      const bf16x8 kf1 = *(const bf16x8*)&Ks[rb + ((32 + lg * 8) ^ kxor)];
      f32x4 z = {};
      z = __builtin_amdgcn_mfma_f32_16x16x32_bf16(kf0, qfB0, z, 0, 0, 0);
      z = __builtin_amdgcn_mfma_f32_16x16x32_bf16(kf1, qfB1, z, 0, 0, 0);
      st[h] = z;
    }
#pragma unroll
    for (int h = 0; h < 4; ++h)
#pragma unroll
      for (int j = 0; j < 4; ++j) st[h][j] *= SCL;
    if (c == qt) {
      const int qg = q0 + lr;
#pragma unroll
      for (int h = 0; h < 4; ++h)
#pragma unroll
        for (int j = 0; j < 4; ++j) {
          int sg = sbase + 16 * h + lg * 4 + j;
          if (sg > qg) st[h][j] = -__builtin_inff();
        }
    }
    float vmax = fmaxf(fmaxf(st[0][0], st[0][1]), fmaxf(st[0][2], st[0][3]));
#pragma unroll
    for (int h = 1; h < 4; ++h)
      vmax = fmaxf(vmax, fmaxf(fmaxf(st[h][0], st[h][1]), fmaxf(st[h][2], st[h][3])));
    vmax = fmaxf(vmax, __shfl_xor(vmax, 16));
    vmax = fmaxf(vmax, __shfl_xor(vmax, 32));

    // defer-max (exact, THR=0): only rescale when some row's max actually grew
    if (!__all(vmax <= mrow)) {
      const float mnew = fmaxf(mrow, vmax);
      const float cf = EXP2F(mrow - mnew);
      mrow = mnew;
      lrow *= cf;
      float cfj[4];
#pragma unroll
      for (int j = 0; j < 4; ++j) cfj[j] = __shfl(cf, lg * 4 + j);
#pragma unroll
      for (int nf = 0; nf < 4; ++nf)
#pragma unroll
        for (int j = 0; j < 4; ++j) yacc[nf][j] *= cfj[j];
    }

    float rs = 0.0f;
#pragma unroll
    for (int h = 0; h < 4; ++h) {
      float p0 = EXP2F(st[h][0] - mrow);
      float p1 = EXP2F(st[h][1] - mrow);
      float p2 = EXP2F(st[h][2] - mrow);
      float p3 = EXP2F(st[h][3] - mrow);
      rs += (p0 + p1) + (p2 + p3);
      bf16x4 pk = {(bf16)p0, (bf16)p1, (bf16)p2, (bf16)p3};
      *(bf16x4*)&Plds[w][lr][16 * h + lg * 4] = pk;
    }
    rs += __shfl_xor(rs, 16);
    rs += __shfl_xor(rs, 32);
    lrow += rs;

    const bf16x8 pa0 = *(const bf16x8*)&Plds[w][lr][lg * 8];
    const bf16x8 pa1 = *(const bf16x8*)&Plds[w][lr][32 + lg * 8];
#pragma unroll
    for (int nf = 0; nf < 4; ++nf) {
      const int rb = (nf * 16 + lr) * 64;
      const bf16x8 vf0 = *(const bf16x8*)&Vs[rb + ((lg * 8) ^ kxor)];
      const bf16x8 vf1 = *(const bf16x8*)&Vs[rb + ((32 + lg * 8) ^ kxor)];
      yacc[nf] = __builtin_amdgcn_mfma_f32_16x16x32_bf16(pa0, vf0, yacc[nf], 0, 0, 0);
      yacc[nf] = __builtin_amdgcn_mfma_f32_16x16x32_bf16(pa1, vf1, yacc[nf], 0, 0, 0);
    }
  }

  const float rinv = 1.0f / lrow;
  float linv[4];
#pragma unroll
  for (int j = 0; j < 4; ++j) linv[j] = __shfl(rinv, lg * 4 + j);
  const int b = bh >> 4, h = bh & 15;
#pragma unroll
  for (int nf = 0; nf < 4; ++nf)
#pragma unroll
    for (int j = 0; j < 4; ++j) {
      int qg = q0 + lg * 4 + j;
      Y[((size_t)b * 2048 + qg) * 1024 + h * 64 + nf * 16 + lr] = (bf16)(yacc[nf][j] * linv[j]);
    }
}

extern "C" void kernel_launch(void* const* d_in, const int* in_sizes, int n_in,
                              void* d_out, int out_size, void* d_ws, size_t ws_size,
                              hipStream_t stream) {
  const float* x = (const float*)d_in[0];
  const float* ctx = (const float*)d_in[1];
  const float* q_w = (const float*)d_in[2];
  const float* q_b = (const float*)d_in[3];
  const float* k_w = (const float*)d_in[4];
  const float* k_b = (const float*)d_in[5];
  const float* v_w = (const float*)d_in[6];
  const float* v_b = (const float*)d_in[7];
  const float* o_w = (const float*)d_in[8];
  const float* o_b = (const float*)d_in[9];

  char* ws = (char*)d_ws;
  const size_t MB = 1024 * 1024;
  bf16* xb = (bf16*)(ws + 0);           // [4096][1024] bf16 (x then ctx contiguous)
  bf16* qwt = (bf16*)(ws + 16 * MB);    // 4 transposed weights, 2MB stride
  bf16* Qws = (bf16*)(ws + 24 * MB);    // Q, K, V^T at 8MB stride
  bf16* Kws = (bf16*)(ws + 32 * MB);
  bf16* Vt = (bf16*)(ws + 40 * MB);
  bf16* Yws = (bf16*)(ws + 48 * MB);
  bf16* owt = qwt + 3 * 1048576;

  cvt_kernel<<<8192, 256, 0, stream>>>((const float4*)x, (const float4*)ctx, (bf16x4*)xb);

  dim3 tb(32, 8), tg(32, 32, 4);
  transpose_kernel<<<tg, tb, 0, stream>>>(q_w, k_w, v_w, o_w, qwt);

  bf16* cb = xb + (size_t)4096 * 1024 / 2 * 2;  // ctx half starts at element 4M
  cb = xb + 4194304;
  gemm_qkv_kernel<<<dim3(8, 32, 3), 256, 0, stream>>>(xb, cb, qwt, q_b, k_b, v_b, Qws);

  attn_kernel<<<dim3(32, 32), 256, 0, stream>>>(Qws, Kws, Vt, Yws);

  gemm_o_kernel<<<dim3(8, 32), 256, 0, stream>>>(Yws, owt, o_b, (float*)d_out);
}